// Round 3
// baseline (1151.939 us; speedup 1.0000x reference)
//
#include <hip/hip_runtime.h>
#include <stdint.h>

// Capsule routing, f32. B=32, Nin=2048, Din=16, Nout=64, Dout=32, 3 iterations.
// Round 2: W streamed via global_load_lds (coalesced, pre-swizzled source) into
// double-buffered 64KB half-i LDS buffers; consume with conflict-free ds_read_b128.

#define CB    32
#define NIN   2048
#define DIN   16
#define NOUT  64
#define DOUT  32
#define CHUNK 32
#define NCHUNK (NIN / CHUNK)   // 64
#define G     8
#define NBG   (CB / G)         // 4

// dynamic LDS layout (bytes)
#define BUF0_OFF  0
#define BUF1_OFF  65536
#define SHX_OFF   131072                  // [G][CHUNK][DIN] f32 = 16384 B
#define SHBL_OFF  (SHX_OFF + 16384)       // [G][NOUT] f32 = 2048 B
#define SHRED_OFF (SHBL_OFF + 2048)       // [G][2] f32 = 64 B
#define SMEM_BYTES (SHRED_OFF + 64)       // 149568

#define AS1 __attribute__((address_space(1)))
#define AS3 __attribute__((address_space(3)))

// Stage one 64KB j-half of W_i into LDS. Source granule address is pre-swizzled
// (involution g ^= (g>>4)&7) so the read side is bank-conflict-free while the
// LDS destination stays linear (global_load_lds requirement).
__device__ __forceinline__ void stage_half(const float* __restrict__ W, char* smem,
                                           int bufOff, int i, int H, int w, int l) {
    const size_t gbase = ((size_t)i << 13) + ((size_t)H << 12);   // 16B granules
#pragma unroll
    for (int L = 0; L < 8; ++L) {
        const int o = L * 512 + w * 64 + l;          // LDS granule slot
        const int g = o ^ ((o >> 4) & 7);            // swizzled source granule
        const char* src = (const char*)W + ((gbase + (size_t)g) << 4);
        char* dst = smem + bufOff + (size_t)(L * 512 + w * 64) * 16;  // wave-uniform
        __builtin_amdgcn_global_load_lds((const AS1 unsigned int*)src,
                                         (AS3 unsigned int*)dst, 16, 0, 0);
    }
}

// Compute u_hat (4 b x 4 d rows) for this thread's (jj, dq) from a staged half,
// plus (IT>0) the full logit dot over d via 3-round shfl within the 8-lane d-quad group.
template <int IT>
__device__ __forceinline__ void half_compute(const char* smem, int bufOff,
                                             const float xr[4][16], const float vr[4][4],
                                             float uh[4][4], float lg[4],
                                             int jj, int dq) {
    const int G0 = jj * 128 + dq * 16;
#pragma unroll
    for (int q = 0; q < 16; ++q) {
        const int slot = G0 + (q & 8) + ((q & 7) ^ dq);   // read-side swizzle (matches source)
        const float4 wv = *(const float4*)(smem + bufOff + slot * 16);
        const int r = q >> 2, k0 = (q & 3) * 4;
#pragma unroll
        for (int bb = 0; bb < 4; ++bb)
            uh[bb][r] += wv.x * xr[bb][k0] + wv.y * xr[bb][k0 + 1]
                       + wv.z * xr[bb][k0 + 2] + wv.w * xr[bb][k0 + 3];
    }
    if (IT > 0) {
#pragma unroll
        for (int bb = 0; bb < 4; ++bb) {
            float d = uh[bb][0] * vr[bb][0] + uh[bb][1] * vr[bb][1]
                    + uh[bb][2] * vr[bb][2] + uh[bb][3] * vr[bb][3];
            d += __shfl_xor(d, 1);
            d += __shfl_xor(d, 2);
            d += __shfl_xor(d, 4);
            lg[bb] = d;
        }
    }
}

// Block: 512 threads, (b-group bg, i-chunk). Thread t: jj=t>>4 (j & j+32),
// bh=(t>>3)&1 (b-quad), dq=t&7 (d-quad d0=dq*4).
template <int IT>
__global__ __launch_bounds__(512, 2) void caps_pass(
    const float* __restrict__ x,        // [B, NIN, DIN]
    const float* __restrict__ W,        // [NIN, NOUT, DOUT, DIN]
    const float* __restrict__ v_prev,   // [B, NOUT, DOUT]   (IT>0)
    const float* __restrict__ blog_in,  // [B, NIN, NOUT]    (IT==2)
    float* __restrict__ blog_out,       // [B, NIN, NOUT]    (IT==1)
    float* __restrict__ s_partial)      // [B, NCHUNK, NOUT*DOUT]
{
    extern __shared__ char smem[];
    const int p     = blockIdx.x;                 // 256 blocks, 1/CU
    const int chunk = (p >> 5) * 8 + (p & 7);     // all 4 bg of a chunk on one XCD
    const int bg    = (p & 31) >> 3;
    const int b0    = bg * G;
    const int t     = threadIdx.x;
    const int w     = t >> 6, l = t & 63;
    const int jj    = t >> 4;
    const int bh    = (t >> 3) & 1;
    const int dq    = t & 7;
    const int d0    = dq * 4;

    // stage x slice [G][CHUNK][DIN] into LDS (coalesced-ish, once per block)
#pragma unroll
    for (int rep = 0; rep < 2; ++rep) {
        const int f4  = t * 2 + rep;              // float4 index 0..1023
        const int bb  = f4 >> 7;                  // 128 float4 per b
        const int rem = f4 & 127;
        const float4 xv = *(const float4*)(x + (size_t)(b0 + bb) * NIN * DIN
                                             + (size_t)chunk * CHUNK * DIN + rem * 4);
        *(float4*)(smem + SHX_OFF + f4 * 16) = xv;
    }

    float vreg[2][4][4];
    if (IT > 0) {
#pragma unroll
        for (int js = 0; js < 2; ++js)
#pragma unroll
            for (int bb = 0; bb < 4; ++bb) {
                const int b = b0 + bh * 4 + bb;
                const int j = jj + js * 32;
                const float4 vv = *(const float4*)(v_prev + ((size_t)b * NOUT + j) * DOUT + d0);
                vreg[js][bb][0] = vv.x; vreg[js][bb][1] = vv.y;
                vreg[js][bb][2] = vv.z; vreg[js][bb][3] = vv.w;
            }
    }

    stage_half(W, smem, BUF0_OFF, chunk * CHUNK, 0, w, l);
    __syncthreads();   // buf0 + sh_x ready

    float sacc[2][4][4];
#pragma unroll
    for (int h = 0; h < 2; ++h)
#pragma unroll
        for (int bb = 0; bb < 4; ++bb)
#pragma unroll
            for (int r = 0; r < 4; ++r) sacc[h][bb][r] = 0.f;

#pragma unroll 1
    for (int ii = 0; ii < CHUNK; ++ii) {
        const int i = chunk * CHUNK + ii;

        // x rows for my 4 b's (broadcast LDS reads)
        float xr[4][16];
#pragma unroll
        for (int bb = 0; bb < 4; ++bb)
#pragma unroll
            for (int kq = 0; kq < 4; ++kq) {
                const float4 xv = *(const float4*)(smem + SHX_OFF
                    + (((bh * 4 + bb) * CHUNK + ii) * DIN + kq * 4) * 4);
                xr[bb][kq * 4 + 0] = xv.x; xr[bb][kq * 4 + 1] = xv.y;
                xr[bb][kq * 4 + 2] = xv.z; xr[bb][kq * 4 + 3] = xv.w;
            }

        float uh[2][4][4], lgv[2][4];
#pragma unroll
        for (int bb = 0; bb < 4; ++bb)
#pragma unroll
            for (int r = 0; r < 4; ++r) { uh[0][bb][r] = 0.f; uh[1][bb][r] = 0.f; }

        // prefetch half 1 of this i, compute half 0
        stage_half(W, smem, BUF1_OFF, i, 1, w, l);
        half_compute<IT>(smem, BUF0_OFF, xr, vreg[0], uh[0], lgv[0], jj, dq);
        if (IT > 0) {
#pragma unroll
            for (int bb = 0; bb < 4; ++bb) {
                const int b = b0 + bh * 4 + bb;
                const int j = jj;
                if (IT == 2) lgv[0][bb] += blog_in[((size_t)b * NIN + i) * NOUT + j];
                if (IT == 1 && dq == 0) blog_out[((size_t)b * NIN + i) * NOUT + j] = lgv[0][bb];
                if (dq == 0) *(float*)(smem + SHBL_OFF + ((bh * 4 + bb) * NOUT + j) * 4) = lgv[0][bb];
            }
        }
        __syncthreads();   // A: buf1 ready, buf0 free

        // prefetch half 0 of next i, compute half 1
        if (ii + 1 < CHUNK) stage_half(W, smem, BUF0_OFF, i + 1, 0, w, l);
        half_compute<IT>(smem, BUF1_OFF, xr, vreg[1], uh[1], lgv[1], jj, dq);
        if (IT > 0) {
#pragma unroll
            for (int bb = 0; bb < 4; ++bb) {
                const int b = b0 + bh * 4 + bb;
                const int j = jj + 32;
                if (IT == 2) lgv[1][bb] += blog_in[((size_t)b * NIN + i) * NOUT + j];
                if (IT == 1 && dq == 0) blog_out[((size_t)b * NIN + i) * NOUT + j] = lgv[1][bb];
                if (dq == 0) *(float*)(smem + SHBL_OFF + ((bh * 4 + bb) * NOUT + j) * 4) = lgv[1][bb];
            }
        }
        __syncthreads();   // B: logits in LDS; buf0 prefetch complete

        if (IT == 0) {
#pragma unroll
            for (int h = 0; h < 2; ++h)
#pragma unroll
                for (int bb = 0; bb < 4; ++bb)
#pragma unroll
                    for (int r = 0; r < 4; ++r)
                        sacc[h][bb][r] += uh[h][bb][r] * (1.0f / 64.0f);
        } else {
            // softmax over 64 j's: wave w handles local b = w
            {
                const float val = *(const float*)(smem + SHBL_OFF + (w * NOUT + l) * 4);
                float m = val;
#pragma unroll
                for (int o = 32; o; o >>= 1) m = fmaxf(m, __shfl_xor(m, o));
                float e = __expf(val - m);
#pragma unroll
                for (int o = 32; o; o >>= 1) e += __shfl_xor(e, o);
                if (l == 0) {
                    ((float*)(smem + SHRED_OFF))[w * 2 + 0] = m;
                    ((float*)(smem + SHRED_OFF))[w * 2 + 1] = 1.0f / e;
                }
            }
            __syncthreads();   // C: m, 1/sum ready
#pragma unroll
            for (int h = 0; h < 2; ++h)
#pragma unroll
                for (int bb = 0; bb < 4; ++bb) {
                    const int bl = bh * 4 + bb;
                    const float m   = ((const float*)(smem + SHRED_OFF))[bl * 2 + 0];
                    const float inv = ((const float*)(smem + SHRED_OFF))[bl * 2 + 1];
                    const float c = __expf(lgv[h][bb] - m) * inv;
#pragma unroll
                    for (int r = 0; r < 4; ++r) sacc[h][bb][r] += c * uh[h][bb][r];
                }
        }
    }

    // store partial s: thread owns (j in {jj, jj+32}, d0..d0+3, its 4 b's)
#pragma unroll
    for (int h = 0; h < 2; ++h)
#pragma unroll
        for (int bb = 0; bb < 4; ++bb) {
            const int b = b0 + bh * 4 + bb;
            const int j = jj + h * 32;
            float4 o;
            o.x = sacc[h][bb][0]; o.y = sacc[h][bb][1];
            o.z = sacc[h][bb][2]; o.w = sacc[h][bb][3];
            *(float4*)(s_partial + ((size_t)b * NCHUNK + chunk) * (NOUT * DOUT)
                       + j * DOUT + d0) = o;
        }
}

// Reduce partials over chunks, add bias, squash. One wave per (b,j).
__global__ __launch_bounds__(64) void caps_squash(
    const float* __restrict__ s_partial,  // [B, NCHUNK, NOUT*DOUT]
    const float* __restrict__ bias,       // [NOUT, DOUT]
    float* __restrict__ v_out)            // [B, NOUT, DOUT]
{
    const int bj = blockIdx.x;
    const int b  = bj / NOUT;
    const int j  = bj % NOUT;
    const int t  = threadIdx.x;
    const int d  = t & 31;
    const int h  = t >> 5;

    float sv = 0.f;
    for (int c = h; c < NCHUNK; c += 2)
        sv += s_partial[((size_t)b * NCHUNK + c) * (NOUT * DOUT) + j * DOUT + d];
    sv += __shfl_xor(sv, 32);
    sv += bias[j * DOUT + d];

    float sq = sv * sv;
#pragma unroll
    for (int o = 16; o; o >>= 1) sq += __shfl_xor(sq, o);

    float scale = (sq / (1.0f + sq)) * rsqrtf(sq + 1e-9f);
    float v = scale * sv;
    if (t < 32) v_out[((size_t)b * NOUT + j) * DOUT + d] = v;
}

extern "C" void kernel_launch(void* const* d_in, const int* in_sizes, int n_in,
                              void* d_out, int out_size, void* d_ws, size_t ws_size,
                              hipStream_t stream) {
    const float* x    = (const float*)d_in[0];
    const float* W    = (const float*)d_in[1];
    const float* bias = (const float*)d_in[2];
    float* out = (float*)d_out;

    float* blog  = (float*)d_ws;                                // 16MB
    float* spart = blog + (size_t)CB * NIN * NOUT;              // 16.8MB
    float* vbuf  = spart + (size_t)CB * NCHUNK * NOUT * DOUT;   // 256KB

    // raise dynamic LDS limit (host-side, idempotent, graph-safe)
    hipFuncSetAttribute(reinterpret_cast<const void*>(caps_pass<0>),
                        hipFuncAttributeMaxDynamicSharedMemorySize, SMEM_BYTES);
    hipFuncSetAttribute(reinterpret_cast<const void*>(caps_pass<1>),
                        hipFuncAttributeMaxDynamicSharedMemorySize, SMEM_BYTES);
    hipFuncSetAttribute(reinterpret_cast<const void*>(caps_pass<2>),
                        hipFuncAttributeMaxDynamicSharedMemorySize, SMEM_BYTES);

    dim3 grid(NCHUNK * NBG);   // 256 blocks, 1/CU
    dim3 blockDim(512);

    caps_pass<0><<<grid, blockDim, SMEM_BYTES, stream>>>(x, W, nullptr, nullptr, nullptr, spart);
    caps_squash<<<CB * NOUT, 64, 0, stream>>>(spart, bias, vbuf);

    caps_pass<1><<<grid, blockDim, SMEM_BYTES, stream>>>(x, W, vbuf, nullptr, blog, spart);
    caps_squash<<<CB * NOUT, 64, 0, stream>>>(spart, bias, vbuf);

    caps_pass<2><<<grid, blockDim, SMEM_BYTES, stream>>>(x, W, vbuf, blog, nullptr, spart);
    caps_squash<<<CB * NOUT, 64, 0, stream>>>(spart, bias, out);
}